// Round 5
// baseline (390.083 us; speedup 1.0000x reference)
//
#include <hip/hip_runtime.h>
#include <hip/hip_bf16.h>

// SoftSOM: dists = cdist(x, P); W = softmax(-dists/0.4); blended = W @ P
// N=524288 tokens, D=128, M=256 protos. Outputs: blended [N,128] f32, weights [N,256] f32.
//
// Persistent-block design: 512 blocks x 8 token-tiles (128 tok each).
// P's cross-fragment image (64 KB) is staged to LDS ONCE per block and stays
// resident; per-tile sync uses raw s_barrier + lgkmcnt(0) only, so global
// output stores are never drained inside the loop (vmcnt never forced to 0).

#define N_TOK 524288
#define DIM 128
#define M_PROTO 256
#define TOK_PER_TILE 128
#define TILES_PER_BLK 8
#define NBLK (N_TOK / (TOK_PER_TILE * TILES_PER_BLK))   // 512

typedef __attribute__((ext_vector_type(8))) short bf16x8;
typedef __attribute__((ext_vector_type(4))) float f32x4;
typedef __attribute__((ext_vector_type(4))) unsigned short us4;

typedef __attribute__((address_space(1))) const unsigned int g_u32;
typedef __attribute__((address_space(3))) unsigned int l_u32;

static __device__ __forceinline__ unsigned short f2bf(float f) {
    unsigned int u = __float_as_uint(f);
    u += 0x7FFFu + ((u >> 16) & 1u);   // round-to-nearest-even
    return (unsigned short)(u >> 16);
}
static __device__ __forceinline__ float bf2f(unsigned short h) {
    return __uint_as_float(((unsigned int)h) << 16);
}

// ---------------------------------------------------------------------------
// Prep: P -> bf16 fragments (same layouts as round 4).
//  - Cross  A-frag, SINGLE bf16:  PfH[((kt*16+mf)*64+lane)*8+j], linear==LDS.
//  - Blended B-frag, hi/lo:       PT*[((kt2*8+ng)*64+lane)*8+j].
// Also p_sq[256].
// ---------------------------------------------------------------------------
__global__ void __launch_bounds__(128) prep_kernel(
        const float* __restrict__ P,
        unsigned short* __restrict__ PfH,
        unsigned short* __restrict__ PTfH, unsigned short* __restrict__ PTfL,
        float* __restrict__ psq) {
    int m = blockIdx.x;      // proto 0..255
    int d = threadIdx.x;     // dim   0..127
    float v = P[m * DIM + d];
    unsigned short hi = f2bf(v);
    unsigned short lo = f2bf(v - bf2f(hi));

    int ci = (((d >> 5) * 16 + (m >> 4)) * 64 + (((d >> 3) & 3) * 16 + (m & 15))) * 8 + (d & 7);
    PfH[ci] = hi;

    int bi = (((m >> 5) * 8 + (d >> 4)) * 64 + (((m >> 3) & 3) * 16 + (d & 15))) * 8 + (m & 7);
    PTfH[bi] = hi; PTfL[bi] = lo;

    float s = v * v;
    #pragma unroll
    for (int off = 1; off < 64; off <<= 1) s += __shfl_xor(s, off, 64);
    __shared__ float part[2];
    if ((threadIdx.x & 63) == 0) part[threadIdx.x >> 6] = s;
    __syncthreads();
    if (threadIdx.x == 0) psq[m] = part[0] + part[1];
}

// ---------------------------------------------------------------------------
// Main persistent kernel: 512 threads (8 waves), 128 tokens/tile, 8 tiles.
// LDS: Plds 64 KB (persistent P fragments) + Wl 67.6 KB + psq 1 KB = ~131 KB
//      -> 1 block/CU, 2 waves/SIMD, VGPR capped 256.
// Per tile:
//   convert prefetched X -> bf16 hi/lo regs, x_sq
//   cross S^T = P @ X^T   (A from LDS, conflict-free lane-linear b128 reads)
//   in-register softmax   (lane holds 64 logits of one token, 2 shfl_xor)
//   write W tile (bf16) -> Wl ; [lgkmcnt(0); s_barrier]
//   prefetch next tile's X (T14: latency hides under stores + blended)
//   coalesced f32 weight stores (fire-and-forget)
//   blended = W @ P (A from Wl, B hi/lo from L2-resident PT) + stores
//   [lgkmcnt(0); s_barrier]   (protects Wl reuse; stores never drained)
// ---------------------------------------------------------------------------
__global__ void __launch_bounds__(512, 2) softsom_main(
        const float* __restrict__ X,
        const unsigned short* __restrict__ PfH,
        const unsigned short* __restrict__ PTfH, const unsigned short* __restrict__ PTfL,
        const float* __restrict__ psq,
        float* __restrict__ blended, float* __restrict__ weights) {

    __shared__ __align__(16) unsigned short Plds[32768];    // 64 KB, persistent
    __shared__ __align__(16) unsigned short Wl[128][264];   // 67.6 KB
    __shared__ float s_psq[256];

    const int t = threadIdx.x;
    const int w = t >> 6;          // wave 0..7
    const int l = t & 63;          // lane
    const int c = l & 15;
    const int g = l >> 4;
    const int myrow = w * 16 + c;  // this lane's token row within a tile
    const long blk_base = (long)blockIdx.x * (TOK_PER_TILE * TILES_PER_BLK);

    if (t < 256) s_psq[t] = psq[t];

    // ---- Stage PfH (64 KB) -> LDS once: 64 chunks of 1 KB, 8 per wave ----
    #pragma unroll
    for (int i = 0; i < 8; ++i) {
        int q = w * 8 + i;
        __builtin_amdgcn_global_load_lds(
            (g_u32*)(PfH + q * 512 + l * 8),
            (l_u32*)(Plds + q * 512),
            16, 0, 0);
    }

    // ---- Prefetch X for tile 0 (per-lane row, 2 float4 per k-tile) ----
    float4 xf[8];
    {
        const float* xrow = X + (blk_base + myrow) * DIM;
        #pragma unroll
        for (int kt = 0; kt < 4; ++kt) {
            xf[kt * 2]     = *(const float4*)(xrow + kt * 32 + g * 8);
            xf[kt * 2 + 1] = *(const float4*)(xrow + kt * 32 + g * 8 + 4);
        }
    }

    asm volatile("s_waitcnt vmcnt(0)" ::: "memory");
    __syncthreads();   // one-time full sync: Plds + s_psq ready

    const bf16x8* pth = (const bf16x8*)PTfH;
    const bf16x8* ptl = (const bf16x8*)PTfL;

    for (int it = 0; it < TILES_PER_BLK; ++it) {
        const long tok0 = blk_base + (long)it * TOK_PER_TILE;

        // ---- Convert X to bf16 hi/lo, accumulate x_sq ----
        bf16x8 xh[4], xl[4];
        float ps = 0.f;
        #pragma unroll
        for (int kt = 0; kt < 4; ++kt) {
            float xv[8] = {xf[kt*2].x, xf[kt*2].y, xf[kt*2].z, xf[kt*2].w,
                           xf[kt*2+1].x, xf[kt*2+1].y, xf[kt*2+1].z, xf[kt*2+1].w};
            #pragma unroll
            for (int j = 0; j < 8; ++j) {
                ps += xv[j] * xv[j];
                unsigned short h = f2bf(xv[j]);
                xh[kt][j] = (short)h;
                xl[kt][j] = (short)f2bf(xv[j] - bf2f(h));
            }
        }
        ps += __shfl_xor(ps, 16, 64);
        ps += __shfl_xor(ps, 32, 64);
        const float xq = ps;

        // ---- Cross S^T = P @ X^T (A-frags from resident LDS) ----
        f32x4 acc[16];
        #pragma unroll
        for (int m = 0; m < 16; ++m) acc[m] = (f32x4){0.f, 0.f, 0.f, 0.f};

        #pragma unroll
        for (int kt = 0; kt < 4; ++kt) {
            #pragma unroll
            for (int m = 0; m < 16; ++m) {
                bf16x8 ah = *(const bf16x8*)&Plds[((kt * 16 + m) * 64 + l) * 8];
                acc[m] = __builtin_amdgcn_mfma_f32_16x16x32_bf16(ah, xh[kt], acc[m], 0, 0, 0);
                acc[m] = __builtin_amdgcn_mfma_f32_16x16x32_bf16(ah, xl[kt], acc[m], 0, 0, 0);
            }
        }

        // ---- Softmax over protos (exp2 domain; psq as vec4 reads) ----
        const float K2 = 3.6067376022224085f;  // (1/0.4) * log2(e)
        float mx = -3.4e38f;
        #pragma unroll
        for (int m = 0; m < 16; ++m) {
            f32x4 pq = *(const f32x4*)&s_psq[m * 16 + g * 4];
            #pragma unroll
            for (int r = 0; r < 4; ++r) {
                float s2 = fmaxf(xq + pq[r] - 2.f * acc[m][r], 0.f);
                float lg = -sqrtf(s2) * K2;
                acc[m][r] = lg;
                mx = fmaxf(mx, lg);
            }
        }
        mx = fmaxf(mx, __shfl_xor(mx, 16, 64));
        mx = fmaxf(mx, __shfl_xor(mx, 32, 64));
        float sum = 0.f;
        #pragma unroll
        for (int m = 0; m < 16; ++m) {
            #pragma unroll
            for (int r = 0; r < 4; ++r) {
                float p = exp2f(acc[m][r] - mx);
                acc[m][r] = p;
                sum += p;
            }
        }
        sum += __shfl_xor(sum, 16, 64);
        sum += __shfl_xor(sum, 32, 64);
        const float inv = 1.0f / sum;

        // ---- Write W tile (bf16) -> Wl ----
        #pragma unroll
        for (int m = 0; m < 16; ++m) {
            us4 wv = {f2bf(acc[m][0] * inv), f2bf(acc[m][1] * inv),
                      f2bf(acc[m][2] * inv), f2bf(acc[m][3] * inv)};
            *(us4*)&Wl[myrow][m * 16 + g * 4] = wv;
        }

        asm volatile("s_waitcnt lgkmcnt(0)" ::: "memory");
        __builtin_amdgcn_s_barrier();            // Wl visible to all waves
        __builtin_amdgcn_sched_barrier(0);

        // ---- Prefetch next tile's X (covers under stores + blended) ----
        if (it + 1 < TILES_PER_BLK) {
            const float* xrow = X + (tok0 + TOK_PER_TILE + myrow) * DIM;
            #pragma unroll
            for (int kt = 0; kt < 4; ++kt) {
                xf[kt * 2]     = *(const float4*)(xrow + kt * 32 + g * 8);
                xf[kt * 2 + 1] = *(const float4*)(xrow + kt * 32 + g * 8 + 4);
            }
        }

        // ---- Coalesced f32 weight stores (wave w owns rows i*8+w) ----
        {
            float* wout = weights + tok0 * M_PROTO;
            #pragma unroll
            for (int i = 0; i < 16; ++i) {
                int row = i * 8 + w;
                us4 wv = *(const us4*)&Wl[row][l * 4];
                float4 o = {bf2f(wv[0]), bf2f(wv[1]), bf2f(wv[2]), bf2f(wv[3])};
                *(float4*)&wout[row * M_PROTO + l * 4] = o;
            }
        }

        // ---- Blended = W @ P (K=256; wave w owns cols w*16..w*16+15) ----
        f32x4 acc2[8];
        #pragma unroll
        for (int m = 0; m < 8; ++m) acc2[m] = (f32x4){0.f, 0.f, 0.f, 0.f};

        #pragma unroll
        for (int kt = 0; kt < 8; ++kt) {
            bf16x8 bh = pth[(kt * 8 + w) * 64 + l];
            bf16x8 bl = ptl[(kt * 8 + w) * 64 + l];
            #pragma unroll
            for (int m = 0; m < 8; ++m) {
                bf16x8 aw = *(const bf16x8*)&Wl[m * 16 + c][kt * 32 + g * 8];
                acc2[m] = __builtin_amdgcn_mfma_f32_16x16x32_bf16(aw, bh, acc2[m], 0, 0, 0);
                acc2[m] = __builtin_amdgcn_mfma_f32_16x16x32_bf16(aw, bl, acc2[m], 0, 0, 0);
            }
        }

        {
            float* bout = blended + tok0 * DIM;
            #pragma unroll
            for (int m = 0; m < 8; ++m)
                #pragma unroll
                for (int r = 0; r < 4; ++r) {
                    int row = m * 16 + g * 4 + r;
                    int d   = w * 16 + c;
                    bout[row * DIM + d] = acc2[m][r];
                }
        }

        asm volatile("s_waitcnt lgkmcnt(0)" ::: "memory");
        __builtin_amdgcn_s_barrier();            // Wl reads done before next overwrite
        __builtin_amdgcn_sched_barrier(0);
    }
}

extern "C" void kernel_launch(void* const* d_in, const int* in_sizes, int n_in,
                              void* d_out, int out_size, void* d_ws, size_t ws_size,
                              hipStream_t stream) {
    const float* x = (const float*)d_in[0];
    const float* protos = (const float*)d_in[1];

    float* out = (float*)d_out;
    float* blended = out;                               // [N,128]
    float* weights = out + (size_t)N_TOK * DIM;         // [N,256]

    unsigned short* PfH  = (unsigned short*)d_ws;       // 32768 elems each
    unsigned short* PTfH = PfH  + 32768;
    unsigned short* PTfL = PTfH + 32768;
    float*          psq  = (float*)(PTfL + 32768);      // 256 f32

    prep_kernel<<<M_PROTO, DIM, 0, stream>>>(protos, PfH, PTfH, PTfL, psq);
    softsom_main<<<NBLK, 512, 0, stream>>>(x, PfH, PTfH, PTfL, psq,
                                           blended, weights);
}

// Round 6
// 301.156 us; speedup vs baseline: 1.2953x; 1.2953x over previous
//
#include <hip/hip_runtime.h>
#include <hip/hip_bf16.h>

// SoftSOM: dists = cdist(x, P); W = softmax(-dists/0.4); blended = W @ P
// N=524288 tokens, D=128, M=256 protos. Outputs: blended [N,128] f32, weights [N,256] f32.
//
// Round-4 structure (4096 blocks x 128 tok, 512 thr, 2 blocks/CU) with:
//  - weights stored straight from registers as exact f32 (no LDS read-back)
//  - W in LDS only as fragment-linear bf16 (blended A-frags: lane-linear b128)
//  - proper barrier between cross (Plds reads) and Wfrag writes (alias fix)
//  - blended B-frags hoisted above the barrier

#define N_TOK 524288
#define DIM 128
#define M_PROTO 256

typedef __attribute__((ext_vector_type(8))) short bf16x8;
typedef __attribute__((ext_vector_type(4))) float f32x4;
typedef __attribute__((ext_vector_type(4))) unsigned short us4;

typedef __attribute__((address_space(1))) const unsigned int g_u32;
typedef __attribute__((address_space(3))) unsigned int l_u32;

static __device__ __forceinline__ unsigned short f2bf(float f) {
    unsigned int u = __float_as_uint(f);
    u += 0x7FFFu + ((u >> 16) & 1u);   // round-to-nearest-even
    return (unsigned short)(u >> 16);
}
static __device__ __forceinline__ float bf2f(unsigned short h) {
    return __uint_as_float(((unsigned int)h) << 16);
}

// ---------------------------------------------------------------------------
// Prep: P -> bf16 fragments (layouts unchanged from round 4).
//  - Cross  A-frag, SINGLE bf16:  PfH[((kt*16+mf)*64+lane)*8+j], linear==LDS.
//  - Blended B-frag, hi/lo:       PT*[((kt2*8+ng)*64+lane)*8+j].
// Also p_sq[256].
// ---------------------------------------------------------------------------
__global__ void __launch_bounds__(128) prep_kernel(
        const float* __restrict__ P,
        unsigned short* __restrict__ PfH,
        unsigned short* __restrict__ PTfH, unsigned short* __restrict__ PTfL,
        float* __restrict__ psq) {
    int m = blockIdx.x;      // proto 0..255
    int d = threadIdx.x;     // dim   0..127
    float v = P[m * DIM + d];
    unsigned short hi = f2bf(v);
    unsigned short lo = f2bf(v - bf2f(hi));

    int ci = (((d >> 5) * 16 + (m >> 4)) * 64 + (((d >> 3) & 3) * 16 + (m & 15))) * 8 + (d & 7);
    PfH[ci] = hi;

    int bi = (((m >> 5) * 8 + (d >> 4)) * 64 + (((m >> 3) & 3) * 16 + (d & 15))) * 8 + (m & 7);
    PTfH[bi] = hi; PTfL[bi] = lo;

    float s = v * v;
    #pragma unroll
    for (int off = 1; off < 64; off <<= 1) s += __shfl_xor(s, off, 64);
    __shared__ float part[2];
    if ((threadIdx.x & 63) == 0) part[threadIdx.x >> 6] = s;
    __syncthreads();
    if (threadIdx.x == 0) psq[m] = part[0] + part[1];
}

// ---------------------------------------------------------------------------
// Main kernel: 128 tokens/block, 512 threads (8 waves, 16 tok/wave).
// LDS: smem 64 KB = Plds (cross P frags) ALIASED with Wfrag (blended A frags,
//      fragment-linear bf16) + psq 1 KB -> 65.5 KB -> 2 blocks/CU.
// Flow: [stage Plds + prefetch X] vmcnt(0) sync
//       cross S^T = P @ X^T (Plds lane-linear b128; X hi/lo regs)
//       lgkm(0)+barrier  (all Plds reads done before Wfrag overwrites)
//       softmax in-register -> f32 weight stores from regs (16x 16-row/64B)
//       Wfrag writes (8B, 2-way-free) ; hoist 16 blended B-frag loads
//       lgkm(0)+barrier
//       blended = W @ P (Wfrag lane-linear b128; PT hi/lo preloaded) + stores
// ---------------------------------------------------------------------------
__global__ void __launch_bounds__(512, 4) softsom_main(
        const float* __restrict__ X,
        const unsigned short* __restrict__ PfH,
        const unsigned short* __restrict__ PTfH, const unsigned short* __restrict__ PTfL,
        const float* __restrict__ psq,
        float* __restrict__ blended, float* __restrict__ weights) {

    __shared__ __align__(16) unsigned short smem[32768];   // 64 KB: Plds | Wfrag
    __shared__ float s_psq[256];
    unsigned short* Plds  = smem;
    unsigned short* Wfrag = smem;

    const int t = threadIdx.x;
    const int w = t >> 6;          // wave 0..7
    const int l = t & 63;          // lane
    const int c = l & 15;
    const int g = l >> 4;
    const int myrow = w * 16 + c;  // this lane's token row within the tile
    const long base_tok = (long)blockIdx.x * 128;

    // ---- X prefetch (per-lane row, 2 float4 per k-tile) ----
    const float* xrow = X + (base_tok + myrow) * DIM;
    float4 xf[8];
    #pragma unroll
    for (int kt = 0; kt < 4; ++kt) {
        xf[kt * 2]     = *(const float4*)(xrow + kt * 32 + g * 8);
        xf[kt * 2 + 1] = *(const float4*)(xrow + kt * 32 + g * 8 + 4);
    }

    if (t < 256) s_psq[t] = psq[t];

    // ---- Stage PfH (64 KB) -> LDS: 64 chunks of 1 KB, 8 per wave ----
    #pragma unroll
    for (int i = 0; i < 8; ++i) {
        int q = w * 8 + i;
        __builtin_amdgcn_global_load_lds(
            (g_u32*)(PfH + q * 512 + l * 8),
            (l_u32*)(Plds + q * 512),
            16, 0, 0);
    }
    asm volatile("s_waitcnt vmcnt(0)" ::: "memory");
    __syncthreads();

    // ---- Convert X to bf16 hi/lo, accumulate x_sq ----
    bf16x8 xh[4], xl[4];
    float ps = 0.f;
    #pragma unroll
    for (int kt = 0; kt < 4; ++kt) {
        float xv[8] = {xf[kt*2].x, xf[kt*2].y, xf[kt*2].z, xf[kt*2].w,
                       xf[kt*2+1].x, xf[kt*2+1].y, xf[kt*2+1].z, xf[kt*2+1].w};
        #pragma unroll
        for (int j = 0; j < 8; ++j) {
            ps += xv[j] * xv[j];
            unsigned short h = f2bf(xv[j]);
            xh[kt][j] = (short)h;
            xl[kt][j] = (short)f2bf(xv[j] - bf2f(h));
        }
    }
    ps += __shfl_xor(ps, 16, 64);
    ps += __shfl_xor(ps, 32, 64);
    const float xq = ps;

    // ---- Cross S^T = P @ X^T (A-frags from LDS, lane-linear) ----
    f32x4 acc[16];
    #pragma unroll
    for (int m = 0; m < 16; ++m) acc[m] = (f32x4){0.f, 0.f, 0.f, 0.f};

    #pragma unroll
    for (int kt = 0; kt < 4; ++kt) {
        #pragma unroll
        for (int m = 0; m < 16; ++m) {
            bf16x8 ah = *(const bf16x8*)&Plds[((kt * 16 + m) * 64 + l) * 8];
            acc[m] = __builtin_amdgcn_mfma_f32_16x16x32_bf16(ah, xh[kt], acc[m], 0, 0, 0);
            acc[m] = __builtin_amdgcn_mfma_f32_16x16x32_bf16(ah, xl[kt], acc[m], 0, 0, 0);
        }
    }

    // All waves' Plds reads must finish before Wfrag (alias) is written.
    asm volatile("s_waitcnt lgkmcnt(0)" ::: "memory");
    __builtin_amdgcn_s_barrier();
    __builtin_amdgcn_sched_barrier(0);

    // ---- Softmax over protos (exp2 domain) ----
    const float K2 = 3.6067376022224085f;  // (1/0.4) * log2(e)
    float mx = -3.4e38f;
    #pragma unroll
    for (int m = 0; m < 16; ++m) {
        f32x4 pq = *(const f32x4*)&s_psq[m * 16 + g * 4];
        #pragma unroll
        for (int r = 0; r < 4; ++r) {
            float s2 = fmaxf(xq + pq[r] - 2.f * acc[m][r], 0.f);
            float lg = -sqrtf(s2) * K2;
            acc[m][r] = lg;
            mx = fmaxf(mx, lg);
        }
    }
    mx = fmaxf(mx, __shfl_xor(mx, 16, 64));
    mx = fmaxf(mx, __shfl_xor(mx, 32, 64));
    float sum = 0.f;
    #pragma unroll
    for (int m = 0; m < 16; ++m) {
        #pragma unroll
        for (int r = 0; r < 4; ++r) {
            float p = exp2f(acc[m][r] - mx);
            acc[m][r] = p;
            sum += p;
        }
    }
    sum += __shfl_xor(sum, 16, 64);
    sum += __shfl_xor(sum, 32, 64);
    const float inv = 1.0f / sum;

    // ---- Weight stores: exact f32 straight from registers ----
    // per m: 64 lanes write 16 rows x 64B contiguous segments
    {
        float* wout = weights + (base_tok + myrow) * M_PROTO + g * 4;
        #pragma unroll
        for (int m = 0; m < 16; ++m) {
            float4 o = {acc[m][0] * inv, acc[m][1] * inv,
                        acc[m][2] * inv, acc[m][3] * inv};
            *(float4*)&wout[m * 16] = o;
        }
    }

    // ---- Wfrag writes: bf16 W in blended-A fragment order ----
    // lane (c,g), token w*16+c, protos m*16+g*4+r ->
    // Wfrag[(((m>>1)*8 + w)*64 + ((m&1)*2 + (g>>1))*16 + c)*8 + (g&1)*4]
    #pragma unroll
    for (int m = 0; m < 16; ++m) {
        us4 wv = {f2bf(acc[m][0] * inv), f2bf(acc[m][1] * inv),
                  f2bf(acc[m][2] * inv), f2bf(acc[m][3] * inv)};
        int off = (((m >> 1) * 8 + w) * 64 + ((m & 1) * 2 + (g >> 1)) * 16 + c) * 8 + (g & 1) * 4;
        *(us4*)&Wfrag[off] = wv;
    }

    // ---- Hoist blended B-frags (L2-resident PT, independent of LDS) ----
    const bf16x8* pth = (const bf16x8*)PTfH;
    const bf16x8* ptl = (const bf16x8*)PTfL;
    bf16x8 bh[8], bl[8];
    #pragma unroll
    for (int kt = 0; kt < 8; ++kt) {
        bh[kt] = pth[(kt * 8 + w) * 64 + l];
        bl[kt] = ptl[(kt * 8 + w) * 64 + l];
    }

    asm volatile("s_waitcnt lgkmcnt(0)" ::: "memory");
    __builtin_amdgcn_s_barrier();
    __builtin_amdgcn_sched_barrier(0);

    // ---- Blended = W @ P (K=256; wave w owns cols w*16..w*16+15) ----
    f32x4 acc2[8];
    #pragma unroll
    for (int m = 0; m < 8; ++m) acc2[m] = (f32x4){0.f, 0.f, 0.f, 0.f};

    #pragma unroll
    for (int kt = 0; kt < 8; ++kt) {
        #pragma unroll
        for (int m = 0; m < 8; ++m) {
            bf16x8 aw = *(const bf16x8*)&Wfrag[((kt * 8 + m) * 64 + l) * 8];
            acc2[m] = __builtin_amdgcn_mfma_f32_16x16x32_bf16(aw, bh[kt], acc2[m], 0, 0, 0);
            acc2[m] = __builtin_amdgcn_mfma_f32_16x16x32_bf16(aw, bl[kt], acc2[m], 0, 0, 0);
        }
    }

    {
        float* bout = blended + base_tok * DIM + w * 16 + c;
        #pragma unroll
        for (int m = 0; m < 8; ++m)
            #pragma unroll
            for (int r = 0; r < 4; ++r) {
                int row = m * 16 + g * 4 + r;
                bout[row * DIM] = acc2[m][r];
            }
    }
}

extern "C" void kernel_launch(void* const* d_in, const int* in_sizes, int n_in,
                              void* d_out, int out_size, void* d_ws, size_t ws_size,
                              hipStream_t stream) {
    const float* x = (const float*)d_in[0];
    const float* protos = (const float*)d_in[1];

    float* out = (float*)d_out;
    float* blended = out;                               // [N,128]
    float* weights = out + (size_t)N_TOK * DIM;         // [N,256]

    unsigned short* PfH  = (unsigned short*)d_ws;       // 32768 elems each
    unsigned short* PTfH = PfH  + 32768;
    unsigned short* PTfL = PTfH + 32768;
    float*          psq  = (float*)(PTfL + 32768);      // 256 f32

    prep_kernel<<<M_PROTO, DIM, 0, stream>>>(protos, PfH, PTfH, PTfL, psq);
    softsom_main<<<N_TOK / 128, 512, 0, stream>>>(x, PfH, PTfH, PTfL, psq,
                                                  blended, weights);
}